// Round 1
// baseline (194.287 us; speedup 1.0000x reference)
//
#include <hip/hip_runtime.h>

// YOLO loss, 3 levels. Inputs (fp32):
//   d_in[0..2] = pred (N=16, C=255, H, W), d_in[3..5] = label (N, H, W, 3, 85)
// Output: d_out = [reg, conf, prob] fp32.
//
// R10: fuse scan+loss into ONE kernel (memset -> fused -> finalize).
// The scan->loss dependency is per-(level,image) (48 lists), not global, so
// instead of a dispatch boundary each conf block scans ITS OWN 256-cell range,
// release-publishes a per-li done-count (wbl2 flushes box stores across the
// non-coherent XCD L2s), overlaps its pred-plane loads with peers' scans, then
// spin-waits + acquire (buffer_inv) before the IoU pass. Pos blocks moved to
// the grid tail (they must wait for scans anyway). Finalize stays separate
// (R8 showed folding it regresses).

#define NIMG 16
#define MAXB 64

// per-level cell counts: N*3*H*W
#define C0 (16 * 3 * 52 * 52)   // 129792
#define C1 (16 * 3 * 26 * 26)   // 32448
#define C2 (16 * 3 * 13 * 13)   // 8112
#define CTOT (C0 + C1 + C2)     // 170352
#define NBLK ((CTOT + 255) / 256)  // 666 conf blocks
#define NPOS 48
#define NALL (NBLK + NPOS)         // 714 total blocks

// cells per (level, image)
#define CPI0 (3 * 52 * 52)      // 8112
#define CPI1 (3 * 26 * 26)      // 2028
#define CPI2 (3 * 13 * 13)      // 507

// workspace layout (bytes); first 512 B zeroed by the memset
#define WS_COUNTS   0                       // 48 ints
#define WS_DONE     192                     // 48 ints (scanned-cell counters)
#define WS_BOXES    512                     // 48*64 float4 = 49152
#define WS_CELLIDS  (512 + 48 * 64 * 16)    // 49664: 48*64 int = 12288
#define WS_PARTIAL  65536                   // float[3][1024]

__device__ __constant__ float d_anchors[3][3][2] = {
    {{12.f, 16.f}, {19.f, 36.f}, {40.f, 28.f}},
    {{36.f, 75.f}, {76.f, 55.f}, {72.f, 146.f}},
    {{142.f, 110.f}, {192.f, 243.f}, {459.f, 401.f}}};

__device__ __forceinline__ float bce_logits(float x, float t) {
    return fmaxf(x, 0.f) - x * t + log1pf(expf(-fabsf(x)));
}

__device__ __forceinline__ int li_cells(int li) {
    int lv = li >> 4;
    return lv == 0 ? CPI0 : (lv == 1 ? CPI1 : CPI2);
}
__device__ __forceinline__ int li_of(int g) {           // global cell -> li (0..47)
    if (g < C0) return g / CPI0;
    if (g < C0 + C1) return 16 + (g - C0) / CPI1;
    return 32 + (g - C0 - C1) / CPI2;
}
__device__ __forceinline__ int li_start(int li) {       // first global cell of li
    int lv = li >> 4, n = li & 15;
    if (lv == 0) return n * CPI0;
    if (lv == 1) return C0 + n * CPI1;
    return C0 + C1 + n * CPI2;
}

// ---------------- fused: scan (per-block range) + conf + positives ----------
__global__ __launch_bounds__(256, 3) void yolo_fused(
        const float* __restrict__ f0,
        const float* __restrict__ f1,
        const float* __restrict__ f2,
        const float* __restrict__ l0,
        const float* __restrict__ l1,
        const float* __restrict__ l2,
        int* __restrict__ counts,
        int* __restrict__ done,
        float4* __restrict__ boxes,
        int* __restrict__ cellids,
        float* __restrict__ partial) {
    if (blockIdx.x < NBLK) {
        // ================= conf block: scan -> publish -> conf ==============
        int gid = blockIdx.x * 256 + threadIdx.x;
        bool act = gid < CTOT;

        // ---- phase A: scan labels (label-record order), compact positives ----
        if (act) {
            const float* lab; int lcell, cpi, libase;
            if (gid < C0)           { lab = l0; lcell = gid;           cpi = CPI0; libase = 0;  }
            else if (gid < C0 + C1) { lab = l1; lcell = gid - C0;      cpi = CPI1; libase = 16; }
            else                    { lab = l2; lcell = gid - C0 - C1; cpi = CPI2; libase = 32; }
            const float* lp = lab + (size_t)lcell * 85;
            float c = lp[4];                 // the only label load for 99.92%
            if (c > 0.f) {
                int li = libase + lcell / cpi;
                int p = atomicAdd(&counts[li], 1);
                if (p < MAXB) {
                    float4 b;
                    b.x = lp[0]; b.y = lp[1]; b.z = lp[2]; b.w = lp[3];
                    boxes[li * MAXB + p] = b;       // plain stores: release wbl2
                    cellids[li * MAXB + p] = lcell; // below flushes them
                }
            }
        }
        __syncthreads();   // all box/cellid stores of this block are in L2

        // ---- publish: per-li scanned-cell counts (block spans <=2 lis) ----
        int s = blockIdx.x * 256;
        int e = min(s + 256, CTOT);
        int liA = li_of(s), liB = li_of(e - 1);
        if (threadIdx.x == 0) {
            if (liA == liB) {
                __hip_atomic_fetch_add(&done[liA], e - s, __ATOMIC_RELEASE, __HIP_MEMORY_SCOPE_AGENT);
            } else {
                int b = li_start(liB);
                __hip_atomic_fetch_add(&done[liA], b - s, __ATOMIC_RELEASE, __HIP_MEMORY_SCOPE_AGENT);
                __hip_atomic_fetch_add(&done[liB], e - b, __ATOMIC_RELEASE, __HIP_MEMORY_SCOPE_AGENT);
            }
        }

        // ---- phase B: pred planes + box-independent math (overlaps peers' scans)
        int level = 0, W = 52, HW = 2704; float stride = 8.f;
        const float* f = f0; int lvbase = 0;
        if (gid >= C0 + C1)  { level = 2; f = f2; W = 13; HW = 169; stride = 32.f; lvbase = C0 + C1; }
        else if (gid >= C0)  { level = 1; f = f1; W = 26; HW = 676; stride = 16.f; lvbase = C0; }
        int cell = act ? gid - lvbase : 0;
        int hw = cell % HW, na = cell / HW;
        int a = na % 3, n = na / 3;
        int w = hw % W, h = hw / W;
        float rc = 0.f, px = 0.f, py = 0.f, pw = 0.f, ph = 0.f;
        if (act) {
            const float* fp = f + (size_t)n * 255 * HW + (size_t)a * 85 * HW + hw;
            float rx = fp[0];
            float ry = fp[HW];
            float rw_ = fp[2 * HW];
            float rh = fp[3 * HW];
            rc = fp[4 * HW];
            px = (1.f / (1.f + expf(-rx)) + (float)w) * stride;
            py = (1.f / (1.f + expf(-ry)) + (float)h) * stride;
            pw = expf(rw_) * d_anchors[level][a][0];
            ph = expf(rh) * d_anchors[level][a][1];
        }
        float parea = pw * ph;
        float pl = px - pw * 0.5f, pr = px + pw * 0.5f;
        float pt = py - ph * 0.5f, pbm = py + ph * 0.5f;
        int cell_lab = (n * HW + hw) * 3 + a;
        int li = level * NIMG + n;

        // ---- wait until this block's li lists are complete ----
        if (threadIdx.x == 0) {
            while (__hip_atomic_load(&done[liA], __ATOMIC_RELAXED, __HIP_MEMORY_SCOPE_AGENT) < li_cells(liA))
                __builtin_amdgcn_s_sleep(1);
            if (liB != liA)
                while (__hip_atomic_load(&done[liB], __ATOMIC_RELAXED, __HIP_MEMORY_SCOPE_AGENT) < li_cells(liB))
                    __builtin_amdgcn_s_sleep(1);
        }
        __syncthreads();
        __builtin_amdgcn_fence(__ATOMIC_ACQUIRE, "agent");  // inv caches before list reads

        // ---- phase C: IoU vs compacted boxes, conf loss ----
        float conf = 0.f;
        if (act) {
            int m = counts[li];
            if (m > MAXB) m = MAXB;
            int bbase = li * MAXB;
            float maxiou = 0.f;
            bool ispos = false;
            for (int i = 0; i < m; ++i) {
                float4 b = boxes[bbase + i];
                if (cellids[bbase + i] == cell_lab) ispos = true;
                float tl = b.x - b.z * 0.5f, tr = b.x + b.z * 0.5f;
                float tt = b.y - b.w * 0.5f, tb = b.y + b.w * 0.5f;
                float iw = fmaxf(fminf(pr, tr) - fmaxf(pl, tl), 0.f);
                float ih = fmaxf(fminf(pbm, tb) - fmaxf(pt, tt), 0.f);
                float inter = iw * ih;
                float uni = parea + b.z * b.w - inter;
                maxiou = fmaxf(maxiou, inter / fmaxf(uni, 1e-9f));
            }
            if (ispos)              conf = bce_logits(rc, 1.f);
            else if (maxiou < 0.5f) conf = bce_logits(rc, 0.f);
        }
        int lane = threadIdx.x & 63, wid = threadIdx.x >> 6;
        for (int off = 32; off > 0; off >>= 1) conf += __shfl_down(conf, off);
        __shared__ float scr[4];
        if (lane == 0) scr[wid] = conf;
        __syncthreads();
        if (threadIdx.x == 0)
            partial[1 * 1024 + blockIdx.x] = scr[0] + scr[1] + scr[2] + scr[3];
    } else {
        // ================= positive block: one wave per box =================
        int pb = blockIdx.x - NBLK;          // 0..47 == li
        int lane = threadIdx.x & 63, wid = threadIdx.x >> 6;
        int lv = pb / NIMG, n = pb % NIMG;
        const float *f, *lab;
        int Wp, HWp; float strp;
        if (lv == 0)      { f = f0; lab = l0; Wp = 52; HWp = 52 * 52; strp = 8.f; }
        else if (lv == 1) { f = f1; lab = l1; Wp = 26; HWp = 26 * 26; strp = 16.f; }
        else              { f = f2; lab = l2; Wp = 13; HWp = 13 * 13; strp = 32.f; }

        if (threadIdx.x == 0)
            while (__hip_atomic_load(&done[pb], __ATOMIC_RELAXED, __HIP_MEMORY_SCOPE_AGENT) < li_cells(pb))
                __builtin_amdgcn_s_sleep(1);
        __syncthreads();
        __builtin_amdgcn_fence(__ATOMIC_ACQUIRE, "agent");

        int m = counts[pb];
        if (m > MAXB) m = MAXB;
        int bbase = pb * MAXB;

        float reg_acc = 0.f, prob_acc = 0.f;
        for (int i = wid; i < m; i += 4) {   // one wave per positive box
            int pcell = cellids[bbase + i];  // (n*HW + hw)*3 + a
            float4 b = boxes[bbase + i];
            int a = pcell % 3;
            int hw = (pcell / 3) % HWp;
            int w = hw % Wp;
            int h = hw / Wp;
            const float* fp = f + ((size_t)n * 255 + (size_t)a * 85) * HWp + hw;
            const float* lp = lab + (size_t)pcell * 85;

            // lanes 0..39: prob ch (5+lane) & (45+lane); lanes 40..43: raw xy/wh
            int ch1 = (lane < 40) ? (5 + lane) : ((lane < 44) ? (lane - 40) : 0);
            float g1 = fp[(size_t)ch1 * HWp];
            float g2 = fp[(size_t)((lane < 40) ? (45 + lane) : 0) * HWp];
            float t1 = lp[(lane < 40) ? (5 + lane) : 0];
            float t2 = lp[(lane < 40) ? (45 + lane) : 0];

            float pp = (lane < 40) ? (bce_logits(g1, t1) + bce_logits(g2, t2)) : 0.f;
            for (int off = 32; off > 0; off >>= 1) pp += __shfl_down(pp, off);

            float prx = __shfl(g1, 40);
            float pry = __shfl(g1, 41);
            float prw = __shfl(g1, 42);
            float prh = __shfl(g1, 43);
            if (lane == 0) {
                prob_acc += pp;
                float aw = d_anchors[lv][a][0];
                float ah = d_anchors[lv][a][1];
                float ox = b.x / strp - (float)w;
                float oy = b.y / strp - (float)h;
                float ow = logf(b.z / aw + 1e-7f);
                float oh = logf(b.w / ah + 1e-7f);
                float scale = 2.f - b.z * b.w * (1.f / (416.f * 416.f));
                float dw = prw - ow, dh = prh - oh;
                reg_acc += scale * (bce_logits(prx, ox) + bce_logits(pry, oy))
                         + scale * 0.5f * (dw * dw + dh * dh);
            }
        }
        __shared__ float sp[2][4];
        if (lane == 0) { sp[0][wid] = reg_acc; sp[1][wid] = prob_acc; }
        __syncthreads();
        if (threadIdx.x == 0) {
            partial[0 * 1024 + pb] = sp[0][0] + sp[0][1] + sp[0][2] + sp[0][3];
            partial[2 * 1024 + pb] = sp[1][0] + sp[1][1] + sp[1][2] + sp[1][3];
        }
    }
}

// ---------------- finalize (1 block) ----------------
__global__ void finalize(const float* __restrict__ partial,
                         float* __restrict__ out) {
    float a0 = 0.f, a1 = 0.f, a2 = 0.f;
    for (int i = threadIdx.x; i < NBLK; i += 256) {
        a1 += partial[1 * 1024 + i];
        if (i < NPOS) {
            a0 += partial[0 * 1024 + i];
            a2 += partial[2 * 1024 + i];
        }
    }
    for (int off = 32; off > 0; off >>= 1) {
        a0 += __shfl_down(a0, off);
        a1 += __shfl_down(a1, off);
        a2 += __shfl_down(a2, off);
    }
    __shared__ float s[3][4];
    int lane = threadIdx.x & 63;
    int wid = threadIdx.x >> 6;
    if (lane == 0) { s[0][wid] = a0; s[1][wid] = a1; s[2][wid] = a2; }
    __syncthreads();
    if (threadIdx.x == 0) {
        out[0] = (s[0][0] + s[0][1] + s[0][2] + s[0][3]) * (1.f / 16.f);
        out[1] = (s[1][0] + s[1][1] + s[1][2] + s[1][3]) * (1.f / 16.f);
        out[2] = (s[2][0] + s[2][1] + s[2][2] + s[2][3]) * (1.f / 16.f);
    }
}

extern "C" void kernel_launch(void* const* d_in, const int* in_sizes, int n_in,
                              void* d_out, int out_size, void* d_ws, size_t ws_size,
                              hipStream_t stream) {
    const float* f0 = (const float*)d_in[0];
    const float* f1 = (const float*)d_in[1];
    const float* f2 = (const float*)d_in[2];
    const float* l0 = (const float*)d_in[3];
    const float* l1 = (const float*)d_in[4];
    const float* l2 = (const float*)d_in[5];
    float* out = (float*)d_out;

    int*    counts  = (int*)((char*)d_ws + WS_COUNTS);
    int*    done    = (int*)((char*)d_ws + WS_DONE);
    float4* boxes   = (float4*)((char*)d_ws + WS_BOXES);
    int*    cellids = (int*)((char*)d_ws + WS_CELLIDS);
    float*  partial = (float*)((char*)d_ws + WS_PARTIAL);

    hipMemsetAsync(d_ws, 0, 512, stream);   // zero counts + done

    yolo_fused<<<NALL, 256, 0, stream>>>(f0, f1, f2, l0, l1, l2,
                                         counts, done, boxes, cellids, partial);
    finalize<<<1, 256, 0, stream>>>(partial, out);
}

// Round 3
// 137.737 us; speedup vs baseline: 1.4106x; 1.4106x over previous
//
#include <hip/hip_runtime.h>

// YOLO loss, 3 levels. Inputs (fp32):
//   d_in[0..2] = pred (N=16, C=255, H, W), d_in[3..5] = label (N, H, W, 3, 85)
// Output: d_out = [reg, conf, prob] fp32.
//
// R12 = R11 resubmit (bench infra failed; kernel audited: no spins, no
// deadlock path, graph-capture safe). Structure:
// R9 champion (memset -> scan -> loss) + FENCE-FREE finalize fold.
// R10 post-mortem: fusing scan+loss with release/acquire handshakes cost
// ~55 us (666 buffer_wbl2 + 714 cache-invalidates + residency-edge spin
// serialization). R8 post-mortem (re-read): its regression was the per-block
// device FENCE (wbl2), not the atomics.
// This round keeps the proven 2-kernel pipeline and folds ONLY finalize into
// loss_fused using:
//   - relaxed AGENT-scope atomic stores for partials (sc1 write-through; no
//     L2 writeback, coherent across XCDs by construction),
//   - s_waitcnt vmcnt(0) + ONE relaxed agent fetch_add arrival ticket,
//   - last-arriving block re-reads partials with relaxed agent atomic loads
//     (cache-bypassing) and reduces in finalize's EXACT order -> bit-identical
//     result, no fences anywhere, no spins.

#define NIMG 16
#define MAXB 64

// per-level cell counts: N*3*H*W
#define C0 (16 * 3 * 52 * 52)   // 129792
#define C1 (16 * 3 * 26 * 26)   // 32448
#define C2 (16 * 3 * 13 * 13)   // 8112
#define CTOT (C0 + C1 + C2)     // 170352
#define NBLK ((CTOT + 255) / 256)  // 666 conf blocks
#define NPOS 48
#define NALL (NBLK + NPOS)         // 714 total blocks

// workspace layout (bytes); first 512 B zeroed by the memset
#define WS_COUNTS   0           // 48 ints
#define WS_TICKET   192         // 1 int (arrival counter)
#define WS_BOXES    512         // 48*64 float4 = 49152
#define WS_CELLIDS  (512 + 48 * 64 * 16)   // 49664: 48*64 int = 12288
#define WS_PARTIAL  65536       // float[3][1024]: [0]=reg(48), [1]=conf(666), [2]=prob(48)

__device__ __constant__ float d_anchors[3][3][2] = {
    {{12.f, 16.f}, {19.f, 36.f}, {40.f, 28.f}},
    {{36.f, 75.f}, {76.f, 55.f}, {72.f, 146.f}},
    {{142.f, 110.f}, {192.f, 243.f}, {459.f, 401.f}}};

__device__ __forceinline__ float bce_logits(float x, float t) {
    return fmaxf(x, 0.f) - x * t + log1pf(expf(-fabsf(x)));
}

// coherent (cross-XCD) helpers: relaxed agent-scope atomics = sc1 ops,
// no wbl2 / no inv on the critical path.
__device__ __forceinline__ void coh_store(float* p, float v) {
    __hip_atomic_store(p, v, __ATOMIC_RELAXED, __HIP_MEMORY_SCOPE_AGENT);
}
__device__ __forceinline__ float coh_load(const float* p) {
    return __hip_atomic_load(p, __ATOMIC_RELAXED, __HIP_MEMORY_SCOPE_AGENT);
}

// ---------------- Kernel A: conf-only gather + positive compaction ----------
__global__ void scan_labels(const float* __restrict__ l0,
                            const float* __restrict__ l1,
                            const float* __restrict__ l2,
                            int* __restrict__ counts,
                            float4* __restrict__ boxes,
                            int* __restrict__ cellids) {
    int rec = blockIdx.x * blockDim.x + threadIdx.x;
    if (rec >= CTOT) return;

    const float* lab;
    int level, cell, hw3;
    if (rec < C0)           { level = 0; cell = rec;           lab = l0; hw3 = 3 * 52 * 52; }
    else if (rec < C0 + C1) { level = 1; cell = rec - C0;      lab = l1; hw3 = 3 * 26 * 26; }
    else                    { level = 2; cell = rec - C0 - C1; lab = l2; hw3 = 3 * 13 * 13; }

    const float* lp = lab + (size_t)cell * 85;
    float c = lp[4];                     // the only load for 99.92% of threads
    if (c > 0.f) {
        int n = cell / hw3;
        int p = atomicAdd(&counts[level * NIMG + n], 1);
        if (p < MAXB) {
            float4 b;
            b.x = lp[0]; b.y = lp[1]; b.z = lp[2]; b.w = lp[3];
            boxes[(level * NIMG + n) * MAXB + p] = b;
            cellids[(level * NIMG + n) * MAXB + p] = cell;
        }
    }
}

// ---------------- Kernel B: pos (0..47) + conf (48..713) + folded finalize --
__global__ __launch_bounds__(256) void loss_fused(
        const float* __restrict__ f0,
        const float* __restrict__ f1,
        const float* __restrict__ f2,
        const float* __restrict__ l0,
        const float* __restrict__ l1,
        const float* __restrict__ l2,
        const int* __restrict__ counts,
        const float4* __restrict__ boxes,
        const int* __restrict__ cellids,
        float* __restrict__ partial,
        int* __restrict__ ticket,
        float* __restrict__ out) {
    int lane = threadIdx.x & 63;
    int wid = threadIdx.x >> 6;
    __shared__ int s_last;

    if (blockIdx.x < NPOS) {
        // ---- positives: one wave per box ----
        int pb = blockIdx.x;                 // 0..47 = (level, image)
        int lv = pb / NIMG;
        int n = pb % NIMG;
        const float *f, *lab;
        int Wp, HWp; float strp;
        if (lv == 0)      { f = f0; lab = l0; Wp = 52; HWp = 52 * 52; strp = 8.f; }
        else if (lv == 1) { f = f1; lab = l1; Wp = 26; HWp = 26 * 26; strp = 16.f; }
        else              { f = f2; lab = l2; Wp = 13; HWp = 13 * 13; strp = 32.f; }

        int m = counts[pb];
        if (m > MAXB) m = MAXB;
        int bbase = pb * MAXB;

        float reg_acc = 0.f, prob_acc = 0.f;
        for (int i = wid; i < m; i += 4) {   // one wave per positive box
            int pcell = cellids[bbase + i];  // (n*HW + hw)*3 + a
            float4 b = boxes[bbase + i];
            int a = pcell % 3;
            int hw = (pcell / 3) % HWp;
            int w = hw % Wp;
            int h = hw / Wp;
            const float* fp = f + ((size_t)n * 255 + (size_t)a * 85) * HWp + hw;
            const float* lp = lab + (size_t)pcell * 85;

            // lanes 0..39: prob ch (5+lane) & (45+lane); lanes 40..43: raw xy/wh
            int ch1 = (lane < 40) ? (5 + lane) : ((lane < 44) ? (lane - 40) : 0);
            float g1 = fp[(size_t)ch1 * HWp];
            float g2 = fp[(size_t)((lane < 40) ? (45 + lane) : 0) * HWp];
            float t1 = lp[(lane < 40) ? (5 + lane) : 0];
            float t2 = lp[(lane < 40) ? (45 + lane) : 0];

            float pp = (lane < 40) ? (bce_logits(g1, t1) + bce_logits(g2, t2)) : 0.f;
            for (int off = 32; off > 0; off >>= 1) pp += __shfl_down(pp, off);

            float prx = __shfl(g1, 40);
            float pry = __shfl(g1, 41);
            float prw = __shfl(g1, 42);
            float prh = __shfl(g1, 43);
            if (lane == 0) {
                prob_acc += pp;
                float aw = d_anchors[lv][a][0];
                float ah = d_anchors[lv][a][1];
                float ox = b.x / strp - (float)w;
                float oy = b.y / strp - (float)h;
                float ow = logf(b.z / aw + 1e-7f);
                float oh = logf(b.w / ah + 1e-7f);
                float scale = 2.f - b.z * b.w * (1.f / (416.f * 416.f));
                float dw = prw - ow, dh = prh - oh;
                reg_acc += scale * (bce_logits(prx, ox) + bce_logits(pry, oy))
                         + scale * 0.5f * (dw * dw + dh * dh);
            }
        }
        __shared__ float sp[2][4];
        if (lane == 0) { sp[0][wid] = reg_acc; sp[1][wid] = prob_acc; }
        __syncthreads();
        if (threadIdx.x == 0) {
            // coherent write-through stores (no fence needed for visibility)
            coh_store(&partial[0 * 1024 + pb], sp[0][0] + sp[0][1] + sp[0][2] + sp[0][3]);
            coh_store(&partial[2 * 1024 + pb], sp[1][0] + sp[1][1] + sp[1][2] + sp[1][3]);
        }
    } else {
        // ---- conf loss per cell; no label reads ----
        int cb = blockIdx.x - NPOS;          // 0..NBLK-1
        int gid = cb * blockDim.x + threadIdx.x;
        float conf = 0.f;

        if (gid < CTOT) {
            const float* f;
            int level, cell, W, HW;
            float stride;
            if (gid < C0)           { level = 0; cell = gid;           f = f0; W = 52; HW = 52 * 52; stride = 8.f; }
            else if (gid < C0 + C1) { level = 1; cell = gid - C0;      f = f1; W = 26; HW = 26 * 26; stride = 16.f; }
            else                    { level = 2; cell = gid - C0 - C1; f = f2; W = 13; HW = 13 * 13; stride = 32.f; }

            int hw = cell % HW;
            int na = cell / HW;
            int a = na % 3;
            int n = na / 3;
            int w = hw % W;
            int h = hw / W;
            int cell_lab = (n * HW + hw) * 3 + a;

            const float* fp = f + (size_t)n * 255 * HW + (size_t)a * 85 * HW + hw;
            float rx = fp[0];
            float ry = fp[HW];
            float rw = fp[2 * HW];
            float rh = fp[3 * HW];
            float rc = fp[4 * HW];

            float aw = d_anchors[level][a][0];
            float ah = d_anchors[level][a][1];
            float px = (1.f / (1.f + expf(-rx)) + (float)w) * stride;
            float py = (1.f / (1.f + expf(-ry)) + (float)h) * stride;
            float pw = expf(rw) * aw;
            float ph = expf(rh) * ah;

            int m = counts[level * NIMG + n];
            if (m > MAXB) m = MAXB;
            int base = (level * NIMG + n) * MAXB;
            float parea = pw * ph;
            float pl = px - pw * 0.5f, pr = px + pw * 0.5f;
            float pt = py - ph * 0.5f, pb = py + ph * 0.5f;
            float maxiou = 0.f;
            bool ispos = false;
            for (int i = 0; i < m; ++i) {
                float4 b = boxes[base + i];
                if (cellids[base + i] == cell_lab) ispos = true;
                float tl = b.x - b.z * 0.5f, tr = b.x + b.z * 0.5f;
                float tt = b.y - b.w * 0.5f, tb = b.y + b.w * 0.5f;
                float iw = fmaxf(fminf(pr, tr) - fmaxf(pl, tl), 0.f);
                float ih = fmaxf(fminf(pb, tb) - fmaxf(pt, tt), 0.f);
                float inter = iw * ih;
                float uni = parea + b.z * b.w - inter;
                float iou = inter / fmaxf(uni, 1e-9f);
                maxiou = fmaxf(maxiou, iou);
            }
            if (ispos)              conf = bce_logits(rc, 1.f);
            else if (maxiou < 0.5f) conf = bce_logits(rc, 0.f);
        }

        for (int off = 32; off > 0; off >>= 1) conf += __shfl_down(conf, off);
        __shared__ float sc[4];
        if (lane == 0) sc[wid] = conf;
        __syncthreads();
        if (threadIdx.x == 0)
            coh_store(&partial[1 * 1024 + cb], sc[0] + sc[1] + sc[2] + sc[3]);
    }

    // ---- arrival ticket: last block folds finalize (no fences, no spins) ----
    if (threadIdx.x == 0) {
        // ensure this block's partial store has reached the coherent point
        asm volatile("s_waitcnt vmcnt(0)" ::: "memory");
        int old = __hip_atomic_fetch_add(ticket, 1, __ATOMIC_RELAXED,
                                         __HIP_MEMORY_SCOPE_AGENT);
        s_last = (old == NALL - 1);
    }
    __syncthreads();
    if (!s_last) return;

    // last-arriving block: reduce partials in finalize's EXACT order
    float a0 = 0.f, a1 = 0.f, a2 = 0.f;
    for (int i = threadIdx.x; i < NBLK; i += 256) {
        a1 += coh_load(&partial[1 * 1024 + i]);
        if (i < NPOS) {
            a0 += coh_load(&partial[0 * 1024 + i]);
            a2 += coh_load(&partial[2 * 1024 + i]);
        }
    }
    for (int off = 32; off > 0; off >>= 1) {
        a0 += __shfl_down(a0, off);
        a1 += __shfl_down(a1, off);
        a2 += __shfl_down(a2, off);
    }
    __shared__ float s[3][4];
    if (lane == 0) { s[0][wid] = a0; s[1][wid] = a1; s[2][wid] = a2; }
    __syncthreads();
    if (threadIdx.x == 0) {
        out[0] = (s[0][0] + s[0][1] + s[0][2] + s[0][3]) * (1.f / 16.f);
        out[1] = (s[1][0] + s[1][1] + s[1][2] + s[1][3]) * (1.f / 16.f);
        out[2] = (s[2][0] + s[2][1] + s[2][2] + s[2][3]) * (1.f / 16.f);
    }
}

extern "C" void kernel_launch(void* const* d_in, const int* in_sizes, int n_in,
                              void* d_out, int out_size, void* d_ws, size_t ws_size,
                              hipStream_t stream) {
    const float* f0 = (const float*)d_in[0];
    const float* f1 = (const float*)d_in[1];
    const float* f2 = (const float*)d_in[2];
    const float* l0 = (const float*)d_in[3];
    const float* l1 = (const float*)d_in[4];
    const float* l2 = (const float*)d_in[5];
    float* out = (float*)d_out;

    int*    counts  = (int*)((char*)d_ws + WS_COUNTS);
    int*    ticket  = (int*)((char*)d_ws + WS_TICKET);
    float4* boxes   = (float4*)((char*)d_ws + WS_BOXES);
    int*    cellids = (int*)((char*)d_ws + WS_CELLIDS);
    float*  partial = (float*)((char*)d_ws + WS_PARTIAL);

    hipMemsetAsync(d_ws, 0, 512, stream);   // zero counts + ticket

    scan_labels<<<NBLK, 256, 0, stream>>>(l0, l1, l2, counts, boxes, cellids);
    loss_fused<<<NALL, 256, 0, stream>>>(f0, f1, f2, l0, l1, l2,
                                         counts, boxes, cellids, partial,
                                         ticket, out);
}

// Round 4
// 133.639 us; speedup vs baseline: 1.4538x; 1.0307x over previous
//
#include <hip/hip_runtime.h>

// YOLO loss, 3 levels. Inputs (fp32):
//   d_in[0..2] = pred (N=16, C=255, H, W), d_in[3..5] = label (N, H, W, 3, 85)
// Output: d_out = [reg, conf, prob] fp32.
//
// R13 = restore R9 champion (memset -> scan -> loss_fused -> finalize),
// measured 132.9 us. The full fusion design space is now measured and every
// alternative REGRESSES:
//   R8  (+12 us): fold finalize w/ per-block device fence (wbl2 on exit path).
//   R10 (+55 us): fuse scan+loss w/ release/acquire handshakes (666 wbl2 +
//                 714 invalidates + residency-edge spin serialization).
//   R12 (+5 us):  fence-free finalize fold (relaxed agent atomics + ticket) -
//                 714x {vmcnt(0) + same-line RMW} on block exit + serial tail
//                 reduce on a drained GPU > a 1-block finalize dispatch that
//                 overlaps its launch with loss_fused's tail.
// Conclusion: dispatch boundaries under graph replay are cheaper than any
// in-kernel synchronization replacing them. Chain HBM traffic ~14 MB (~2 us
// at BW roofline): kernels are launch/latency-bound; remaining window time is
// the harness re-poison fill (256 MiB @ 82% HBM peak), not controllable.
//
//  scan:  conf-only gather (one 4B load per cell, stride 340 B) -> compact
//         positive boxes per (level,image). ~11 MB of cachelines.
//  loss:  blocks 0..47 = positives, ONE WAVE per box, prob channels spread
//         across lanes (2 wave-wide gathers, 64 misses in flight);
//         blocks 48..713 = conf loss per cell (coalesced channel planes,
//         zero label reads; membership via compacted cellids).
//  finalize: 1 block reduces partials -> out.

#define NIMG 16
#define MAXB 64

// per-level cell counts: N*3*H*W
#define C0 (16 * 3 * 52 * 52)   // 129792
#define C1 (16 * 3 * 26 * 26)   // 32448
#define C2 (16 * 3 * 13 * 13)   // 8112
#define CTOT (C0 + C1 + C2)     // 170352
#define NBLK ((CTOT + 255) / 256)  // 666 conf blocks
#define NPOS 48
#define NALL (NBLK + NPOS)         // 714 total blocks

// workspace layout (bytes); first 256 B zeroed by the memset
#define WS_COUNTS   0           // 48 ints
#define WS_BOXES    256         // 48*64 float4 = 49152
#define WS_CELLIDS  49408       // 48*64 int    = 12288
#define WS_PARTIAL  65536       // float[3][1024]: [0]=reg(48), [1]=conf(666), [2]=prob(48)

__device__ __constant__ float d_anchors[3][3][2] = {
    {{12.f, 16.f}, {19.f, 36.f}, {40.f, 28.f}},
    {{36.f, 75.f}, {76.f, 55.f}, {72.f, 146.f}},
    {{142.f, 110.f}, {192.f, 243.f}, {459.f, 401.f}}};

__device__ __forceinline__ float bce_logits(float x, float t) {
    return fmaxf(x, 0.f) - x * t + log1pf(expf(-fabsf(x)));
}

// ---------------- Kernel A: conf-only gather + positive compaction ----------
__global__ void scan_labels(const float* __restrict__ l0,
                            const float* __restrict__ l1,
                            const float* __restrict__ l2,
                            int* __restrict__ counts,
                            float4* __restrict__ boxes,
                            int* __restrict__ cellids) {
    int rec = blockIdx.x * blockDim.x + threadIdx.x;
    if (rec >= CTOT) return;

    const float* lab;
    int level, cell, hw3;
    if (rec < C0)           { level = 0; cell = rec;           lab = l0; hw3 = 3 * 52 * 52; }
    else if (rec < C0 + C1) { level = 1; cell = rec - C0;      lab = l1; hw3 = 3 * 26 * 26; }
    else                    { level = 2; cell = rec - C0 - C1; lab = l2; hw3 = 3 * 13 * 13; }

    const float* lp = lab + (size_t)cell * 85;
    float c = lp[4];                     // the only load for 99.92% of threads
    if (c > 0.f) {
        int n = cell / hw3;
        int p = atomicAdd(&counts[level * NIMG + n], 1);
        if (p < MAXB) {
            float4 b;
            b.x = lp[0]; b.y = lp[1]; b.z = lp[2]; b.w = lp[3];
            boxes[(level * NIMG + n) * MAXB + p] = b;
            cellids[(level * NIMG + n) * MAXB + p] = cell;
        }
    }
}

// ---------------- Kernel B: pos (blocks 0..47) + conf (blocks 48..713) ------
__global__ __launch_bounds__(256) void loss_fused(
        const float* __restrict__ f0,
        const float* __restrict__ f1,
        const float* __restrict__ f2,
        const float* __restrict__ l0,
        const float* __restrict__ l1,
        const float* __restrict__ l2,
        const int* __restrict__ counts,
        const float4* __restrict__ boxes,
        const int* __restrict__ cellids,
        float* __restrict__ partial) {
    int lane = threadIdx.x & 63;
    int wid = threadIdx.x >> 6;

    if (blockIdx.x < NPOS) {
        // ---- positives: one wave per box ----
        int pb = blockIdx.x;                 // 0..47 = (level, image)
        int lv = pb / NIMG;
        int n = pb % NIMG;
        const float *f, *lab;
        int Wp, HWp; float strp;
        if (lv == 0)      { f = f0; lab = l0; Wp = 52; HWp = 52 * 52; strp = 8.f; }
        else if (lv == 1) { f = f1; lab = l1; Wp = 26; HWp = 26 * 26; strp = 16.f; }
        else              { f = f2; lab = l2; Wp = 13; HWp = 13 * 13; strp = 32.f; }

        int m = counts[pb];
        if (m > MAXB) m = MAXB;
        int bbase = pb * MAXB;

        float reg_acc = 0.f, prob_acc = 0.f;
        for (int i = wid; i < m; i += 4) {   // one wave per positive box
            int pcell = cellids[bbase + i];  // (n*HW + hw)*3 + a
            float4 b = boxes[bbase + i];
            int a = pcell % 3;
            int hw = (pcell / 3) % HWp;
            int w = hw % Wp;
            int h = hw / Wp;
            const float* fp = f + ((size_t)n * 255 + (size_t)a * 85) * HWp + hw;
            const float* lp = lab + (size_t)pcell * 85;

            // lanes 0..39: prob ch (5+lane) & (45+lane); lanes 40..43: raw xy/wh
            int ch1 = (lane < 40) ? (5 + lane) : ((lane < 44) ? (lane - 40) : 0);
            float g1 = fp[(size_t)ch1 * HWp];
            float g2 = fp[(size_t)((lane < 40) ? (45 + lane) : 0) * HWp];
            float t1 = lp[(lane < 40) ? (5 + lane) : 0];
            float t2 = lp[(lane < 40) ? (45 + lane) : 0];

            float pp = (lane < 40) ? (bce_logits(g1, t1) + bce_logits(g2, t2)) : 0.f;
            for (int off = 32; off > 0; off >>= 1) pp += __shfl_down(pp, off);

            float prx = __shfl(g1, 40);
            float pry = __shfl(g1, 41);
            float prw = __shfl(g1, 42);
            float prh = __shfl(g1, 43);
            if (lane == 0) {
                prob_acc += pp;
                float aw = d_anchors[lv][a][0];
                float ah = d_anchors[lv][a][1];
                float ox = b.x / strp - (float)w;
                float oy = b.y / strp - (float)h;
                float ow = logf(b.z / aw + 1e-7f);
                float oh = logf(b.w / ah + 1e-7f);
                float scale = 2.f - b.z * b.w * (1.f / (416.f * 416.f));
                float dw = prw - ow, dh = prh - oh;
                reg_acc += scale * (bce_logits(prx, ox) + bce_logits(pry, oy))
                         + scale * 0.5f * (dw * dw + dh * dh);
            }
        }
        __shared__ float sp[2][4];
        if (lane == 0) { sp[0][wid] = reg_acc; sp[1][wid] = prob_acc; }
        __syncthreads();
        if (threadIdx.x == 0) {
            partial[0 * 1024 + pb] = sp[0][0] + sp[0][1] + sp[0][2] + sp[0][3];
            partial[2 * 1024 + pb] = sp[1][0] + sp[1][1] + sp[1][2] + sp[1][3];
        }
    } else {
        // ---- conf loss per cell; no label reads ----
        int cb = blockIdx.x - NPOS;          // 0..NBLK-1
        int gid = cb * blockDim.x + threadIdx.x;
        float conf = 0.f;

        if (gid < CTOT) {
            const float* f;
            int level, cell, W, HW;
            float stride;
            if (gid < C0)           { level = 0; cell = gid;           f = f0; W = 52; HW = 52 * 52; stride = 8.f; }
            else if (gid < C0 + C1) { level = 1; cell = gid - C0;      f = f1; W = 26; HW = 26 * 26; stride = 16.f; }
            else                    { level = 2; cell = gid - C0 - C1; f = f2; W = 13; HW = 13 * 13; stride = 32.f; }

            int hw = cell % HW;
            int na = cell / HW;
            int a = na % 3;
            int n = na / 3;
            int w = hw % W;
            int h = hw / W;
            int cell_lab = (n * HW + hw) * 3 + a;

            const float* fp = f + (size_t)n * 255 * HW + (size_t)a * 85 * HW + hw;
            float rx = fp[0];
            float ry = fp[HW];
            float rw = fp[2 * HW];
            float rh = fp[3 * HW];
            float rc = fp[4 * HW];

            float aw = d_anchors[level][a][0];
            float ah = d_anchors[level][a][1];
            float px = (1.f / (1.f + expf(-rx)) + (float)w) * stride;
            float py = (1.f / (1.f + expf(-ry)) + (float)h) * stride;
            float pw = expf(rw) * aw;
            float ph = expf(rh) * ah;

            int m = counts[level * NIMG + n];
            if (m > MAXB) m = MAXB;
            int base = (level * NIMG + n) * MAXB;
            float parea = pw * ph;
            float pl = px - pw * 0.5f, pr = px + pw * 0.5f;
            float pt = py - ph * 0.5f, pb = py + ph * 0.5f;
            float maxiou = 0.f;
            bool ispos = false;
            for (int i = 0; i < m; ++i) {
                float4 b = boxes[base + i];
                if (cellids[base + i] == cell_lab) ispos = true;
                float tl = b.x - b.z * 0.5f, tr = b.x + b.z * 0.5f;
                float tt = b.y - b.w * 0.5f, tb = b.y + b.w * 0.5f;
                float iw = fmaxf(fminf(pr, tr) - fmaxf(pl, tl), 0.f);
                float ih = fmaxf(fminf(pb, tb) - fmaxf(pt, tt), 0.f);
                float inter = iw * ih;
                float uni = parea + b.z * b.w - inter;
                float iou = inter / fmaxf(uni, 1e-9f);
                maxiou = fmaxf(maxiou, iou);
            }
            if (ispos)              conf = bce_logits(rc, 1.f);
            else if (maxiou < 0.5f) conf = bce_logits(rc, 0.f);
        }

        for (int off = 32; off > 0; off >>= 1) conf += __shfl_down(conf, off);
        __shared__ float sc[4];
        if (lane == 0) sc[wid] = conf;
        __syncthreads();
        if (threadIdx.x == 0)
            partial[1 * 1024 + cb] = sc[0] + sc[1] + sc[2] + sc[3];
    }
}

// ---------------- Kernel C: finalize (1 block) ----------------
__global__ void finalize(const float* __restrict__ partial,
                         float* __restrict__ out) {
    float a0 = 0.f, a1 = 0.f, a2 = 0.f;
    for (int i = threadIdx.x; i < NBLK; i += 256) {
        a1 += partial[1 * 1024 + i];
        if (i < NPOS) {
            a0 += partial[0 * 1024 + i];
            a2 += partial[2 * 1024 + i];
        }
    }
    for (int off = 32; off > 0; off >>= 1) {
        a0 += __shfl_down(a0, off);
        a1 += __shfl_down(a1, off);
        a2 += __shfl_down(a2, off);
    }
    __shared__ float s[3][4];
    int lane = threadIdx.x & 63;
    int wid = threadIdx.x >> 6;
    if (lane == 0) { s[0][wid] = a0; s[1][wid] = a1; s[2][wid] = a2; }
    __syncthreads();
    if (threadIdx.x == 0) {
        out[0] = (s[0][0] + s[0][1] + s[0][2] + s[0][3]) * (1.f / 16.f);
        out[1] = (s[1][0] + s[1][1] + s[1][2] + s[1][3]) * (1.f / 16.f);
        out[2] = (s[2][0] + s[2][1] + s[2][2] + s[2][3]) * (1.f / 16.f);
    }
}

extern "C" void kernel_launch(void* const* d_in, const int* in_sizes, int n_in,
                              void* d_out, int out_size, void* d_ws, size_t ws_size,
                              hipStream_t stream) {
    const float* f0 = (const float*)d_in[0];
    const float* f1 = (const float*)d_in[1];
    const float* f2 = (const float*)d_in[2];
    const float* l0 = (const float*)d_in[3];
    const float* l1 = (const float*)d_in[4];
    const float* l2 = (const float*)d_in[5];
    float* out = (float*)d_out;

    int*    counts  = (int*)((char*)d_ws + WS_COUNTS);
    float4* boxes   = (float4*)((char*)d_ws + WS_BOXES);
    int*    cellids = (int*)((char*)d_ws + WS_CELLIDS);
    float*  partial = (float*)((char*)d_ws + WS_PARTIAL);

    hipMemsetAsync(d_ws, 0, 256, stream);   // zero counts

    scan_labels<<<NBLK, 256, 0, stream>>>(l0, l1, l2, counts, boxes, cellids);
    loss_fused<<<NALL, 256, 0, stream>>>(f0, f1, f2, l0, l1, l2,
                                         counts, boxes, cellids, partial);
    finalize<<<1, 256, 0, stream>>>(partial, out);
}